// Round 1
// baseline (175.933 us; speedup 1.0000x reference)
//
#include <hip/hip_runtime.h>

namespace {

constexpr int Bn = 16, An = 3, Cn = 80, NTGT = 200;
constexpr unsigned CH = 85;
constexpr unsigned S0 = 80, S1 = 40, S2 = 20;

constexpr unsigned L0 = (unsigned)Bn * An * S0 * S0 * CH;  // 26,112,000 floats
constexpr unsigned L1 = (unsigned)Bn * An * S1 * S1 * CH;  //  6,528,000
constexpr unsigned L2 = (unsigned)Bn * An * S2 * S2 * CH;  //  1,632,000
constexpr unsigned F0 = L0 / 4, F1 = L1 / 4, F2 = L2 / 4;  // float4 counts
constexpr unsigned FT = F0 + F1 + F2;                      // 8,568,000

constexpr float WO0 = 1.0f / ((float)Bn * An * S0 * S0);
constexpr float WO1 = 1.0f / ((float)Bn * An * S1 * S1);
constexpr float WO2 = 1.0f / ((float)Bn * An * S2 * S2);
constexpr float WC0 = WO0 / (float)Cn;
constexpr float WC1 = WO1 / (float)Cn;
constexpr float WC2 = WO2 / (float)Cn;

__device__ __forceinline__ float softplusf(float x) {
    // log(1 + exp(x)) = max(x,0) + log(1 + exp(-|x|)); 2 HW transcendentals.
    return fmaxf(x, 0.0f) + __logf(1.0f + __expf(-fabsf(x)));
}

__global__ __launch_bounds__(256) void yolo_sum_kernel(
    const float* __restrict__ p0, const float* __restrict__ p1,
    const float* __restrict__ p2, double* __restrict__ acc)
{
    unsigned tid    = blockIdx.x * 256u + threadIdx.x;
    unsigned stride = gridDim.x * 256u;

    float accO = 0.0f;  // sum of w_obj * softplus over obj channel (c==4)
    float accC = 0.0f;  // sum of w_cls * softplus over cls channels (c>4)

    for (unsigned g = tid; g < FT; g += stride) {
        const float4* P; unsigned base; float wo, wc;
        if (g < F0)           { P = (const float4*)p0; base = g;           wo = WO0; wc = WC0; }
        else if (g < F0 + F1) { P = (const float4*)p1; base = g - F0;      wo = WO1; wc = WC1; }
        else                  { P = (const float4*)p2; base = g - F0 - F1; wo = WO2; wc = WC2; }

        float4 v = P[base];
        unsigned c0 = (base * 4u) % CH;
        float vals[4] = {v.x, v.y, v.z, v.w};
        #pragma unroll
        for (int k = 0; k < 4; ++k) {
            unsigned c = c0 + (unsigned)k;
            if (c >= CH) c -= CH;
            if (c >= 4u) {
                float sp = softplusf(vals[k]);
                if (c == 4u) accO += wo * sp;
                else         accC += wc * sp;
            }
        }
    }

    // wave64 butterfly reduce
    #pragma unroll
    for (int off = 32; off > 0; off >>= 1) {
        accO += __shfl_down(accO, off);
        accC += __shfl_down(accC, off);
    }
    __shared__ float sO[4], sC[4];
    int lane = threadIdx.x & 63, wv = threadIdx.x >> 6;
    if (lane == 0) { sO[wv] = accO; sC[wv] = accC; }
    __syncthreads();
    if (threadIdx.x == 0) {
        float o = sO[0] + sO[1] + sO[2] + sO[3];
        float c = sC[0] + sC[1] + sC[2] + sC[3];
        atomicAdd(&acc[0], (double)o);
        atomicAdd(&acc[1], (double)c);
    }
}

// Single-block kernel: dedup targets per cell (scatter-max semantics) and
// subtract the l*z terms at the (at most 200) hot cells per scale.
__global__ __launch_bounds__(256) void yolo_corr_kernel(
    const float* __restrict__ p0, const float* __restrict__ p1,
    const float* __restrict__ p2, const float* __restrict__ tgt,
    double* __restrict__ acc)
{
    __shared__ float tb[NTGT], tc[NTGT], tx[NTGT], ty[NTGT];
    __shared__ int gxs[NTGT], gys[NTGT];
    __shared__ unsigned char vld[NTGT];

    int t = threadIdx.x;
    if (t < NTGT) {
        tb[t] = tgt[t * 6 + 0];
        tc[t] = tgt[t * 6 + 1];
        tx[t] = tgt[t * 6 + 2];
        ty[t] = tgt[t * 6 + 3];
        vld[t] = (tc[t] < (float)Cn) ? 1 : 0;
    }
    __syncthreads();

    const float* preds[3] = {p0, p1, p2};
    const int    SS[3]    = {(int)S0, (int)S1, (int)S2};
    const float  WOs[3]   = {WO0, WO1, WO2};
    const float  WCs[3]   = {WC0, WC1, WC2};

    float corrO = 0.0f, corrC = 0.0f;

    for (int s = 0; s < 3; ++s) {
        int W = SS[s];
        if (t < NTGT) {
            gxs[t] = min((int)floorf(tx[t] * (float)W), W - 1);
            gys[t] = min((int)floorf(ty[t] * (float)W), W - 1);
        }
        __syncthreads();

        if (t < NTGT && vld[t]) {
            int b  = (int)tb[t];
            int cl = (int)tc[t];
            int gx = gxs[t], gy = gys[t];
            bool uo = true, uc = true;  // first-occurrence flags
            for (int j = 0; j < t; ++j) {
                if (!vld[j]) continue;
                if ((int)tb[j] == b && gys[j] == gy && gxs[j] == gx) {
                    uo = false;
                    if ((int)tc[j] == cl) uc = false;
                }
            }
            const float* P = preds[s];
            // index (b, a=0, gy, gx, ch) in (B, A, H, W, 85)
            unsigned cell = (((unsigned)b * An + 0u) * (unsigned)W + (unsigned)gy)
                            * (unsigned)W + (unsigned)gx;
            if (uo) corrO -= P[cell * CH + 4u] * WOs[s];
            if (uc) corrC -= P[cell * CH + 5u + (unsigned)cl] * WCs[s];
        }
        __syncthreads();
    }

    // block reduce
    #pragma unroll
    for (int off = 32; off > 0; off >>= 1) {
        corrO += __shfl_down(corrO, off);
        corrC += __shfl_down(corrC, off);
    }
    __shared__ float rO[4], rC[4];
    int lane = threadIdx.x & 63, wv = threadIdx.x >> 6;
    if (lane == 0) { rO[wv] = corrO; rC[wv] = corrC; }
    __syncthreads();
    if (threadIdx.x == 0) {
        atomicAdd(&acc[0], (double)(rO[0] + rO[1] + rO[2] + rO[3]));
        atomicAdd(&acc[1], (double)(rC[0] + rC[1] + rC[2] + rC[3]));
    }
}

__global__ void yolo_final_kernel(const double* __restrict__ acc,
                                  float* __restrict__ out)
{
    if (threadIdx.x == 0) {
        double obj = acc[0], cls = acc[1];
        out[0] = (float)(obj + 0.5 * cls);  // BOX_W*0 + OBJ_W*obj + CLS_W*cls
        out[1] = 0.0f;                      // total_box
        out[2] = (float)obj;
        out[3] = (float)cls;
    }
}

}  // namespace

extern "C" void kernel_launch(void* const* d_in, const int* in_sizes, int n_in,
                              void* d_out, int out_size, void* d_ws, size_t ws_size,
                              hipStream_t stream)
{
    const float* p0  = (const float*)d_in[0];
    const float* p1  = (const float*)d_in[1];
    const float* p2  = (const float*)d_in[2];
    const float* tgt = (const float*)d_in[3];
    float* out = (float*)d_out;
    double* acc = (double*)d_ws;

    hipMemsetAsync(acc, 0, 2 * sizeof(double), stream);

    yolo_sum_kernel<<<2048, 256, 0, stream>>>(p0, p1, p2, acc);
    yolo_corr_kernel<<<1, 256, 0, stream>>>(p0, p1, p2, tgt, acc);
    yolo_final_kernel<<<1, 64, 0, stream>>>(acc, out);
}

// Round 2
// 57.064 us; speedup vs baseline: 3.0831x; 3.0831x over previous
//
#include <hip/hip_runtime.h>

namespace {

constexpr int Bn = 16, An = 3, Cn = 80, NTGT = 200;
constexpr unsigned CH = 85;
constexpr unsigned S0 = 80, S1 = 40, S2 = 20;

constexpr unsigned L0 = (unsigned)Bn * An * S0 * S0 * CH;  // 26,112,000 floats
constexpr unsigned L1 = (unsigned)Bn * An * S1 * S1 * CH;  //  6,528,000
constexpr unsigned L2 = (unsigned)Bn * An * S2 * S2 * CH;  //  1,632,000
constexpr unsigned F0 = L0 / 4, F1 = L1 / 4, F2 = L2 / 4;  // float4 counts
constexpr unsigned FT = F0 + F1 + F2;                      // 8,568,000

constexpr unsigned GRID = 2048, BLOCK = 256;
constexpr unsigned STRIDE = GRID * BLOCK;                  // 524,288
// 16 strided rounds are always in-bounds; round 17 is the conditional tail.
static_assert(16u * STRIDE <= FT, "main rounds must be in-bounds");
static_assert(17u * STRIDE >= FT, "one tail round must suffice");

constexpr float WO0 = 1.0f / ((float)Bn * An * S0 * S0);
constexpr float WO1 = 1.0f / ((float)Bn * An * S1 * S1);
constexpr float WO2 = 1.0f / ((float)Bn * An * S2 * S2);
constexpr float WC0 = WO0 / (float)Cn;
constexpr float WC1 = WO1 / (float)Cn;
constexpr float WC2 = WO2 / (float)Cn;

__device__ __forceinline__ float softplusf(float x) {
    // log(1+exp(x)) = max(x,0) + log(1+exp(-|x|)); 2 HW transcendentals.
    return fmaxf(x, 0.0f) + __logf(1.0f + __expf(-fabsf(x)));
}

__device__ __forceinline__ void fetch_one(
    unsigned g, const float* __restrict__ p0, const float* __restrict__ p1,
    const float* __restrict__ p2, float4& v, unsigned& c0, float& wo, float& wc)
{
    const float4* P; unsigned base;
    if (g < F0)           { P = (const float4*)p0; base = g;             wo = WO0; wc = WC0; }
    else if (g < F0 + F1) { P = (const float4*)p1; base = g - F0;        wo = WO1; wc = WC1; }
    else                  { P = (const float4*)p2; base = g - (F0 + F1); wo = WO2; wc = WC2; }
    v  = P[base];
    c0 = (g * 4u) % CH;
}

__device__ __forceinline__ void proc_one(
    const float4& v, unsigned c0, float wo, float wc, float& accO, float& accC)
{
    float vals[4] = {v.x, v.y, v.z, v.w};
    #pragma unroll
    for (int k = 0; k < 4; ++k) {
        unsigned c = c0 + (unsigned)k;
        if (c >= CH) c -= CH;
        if (c >= 4u) {
            float sp = softplusf(vals[k]);
            if (c == 4u) accO += wo * sp;
            else         accC += wc * sp;
        }
    }
}

__global__ __launch_bounds__(BLOCK) void yolo_sum_kernel(
    const float* __restrict__ p0, const float* __restrict__ p1,
    const float* __restrict__ p2, float2* __restrict__ part)
{
    unsigned tid = blockIdx.x * BLOCK + threadIdx.x;
    float accO = 0.0f, accC = 0.0f;

    unsigned g = tid;
    #pragma unroll
    for (int r = 0; r < 4; ++r) {
        float4 v[4]; unsigned c0[4]; float wo[4], wc[4];
        #pragma unroll
        for (int k = 0; k < 4; ++k)   // 4 independent loads in flight
            fetch_one(g + (unsigned)k * STRIDE, p0, p1, p2, v[k], c0[k], wo[k], wc[k]);
        #pragma unroll
        for (int k = 0; k < 4; ++k)
            proc_one(v[k], c0[k], wo[k], wc[k], accO, accC);
        g += 4u * STRIDE;
    }
    if (g < FT) {                     // tail round (round 17)
        float4 v; unsigned c0; float wo, wc;
        fetch_one(g, p0, p1, p2, v, c0, wo, wc);
        proc_one(v, c0, wo, wc, accO, accC);
    }

    #pragma unroll
    for (int off = 32; off > 0; off >>= 1) {
        accO += __shfl_down(accO, off);
        accC += __shfl_down(accC, off);
    }
    __shared__ float sO[4], sC[4];
    int lane = threadIdx.x & 63, wv = threadIdx.x >> 6;
    if (lane == 0) { sO[wv] = accO; sC[wv] = accC; }
    __syncthreads();
    if (threadIdx.x == 0)
        part[blockIdx.x] = make_float2(sO[0] + sO[1] + sO[2] + sO[3],
                                       sC[0] + sC[1] + sC[2] + sC[3]);
}

// Single-block correction: dedup targets per cell via packed u32 keys and
// subtract the l*z terms at the <=200 hot cells per scale.
__global__ __launch_bounds__(BLOCK) void yolo_corr_kernel(
    const float* __restrict__ p0, const float* __restrict__ p1,
    const float* __restrict__ p2, const float* __restrict__ tgt,
    float2* __restrict__ part)
{
    __shared__ unsigned keyO[NTGT], keyC[NTGT];

    int t = threadIdx.x;
    float fb = 0.f, fc = 0.f, fx = 0.f, fy = 0.f;
    bool valid = false;
    if (t < NTGT) {
        fb = tgt[t * 6 + 0];
        fc = tgt[t * 6 + 1];
        fx = tgt[t * 6 + 2];
        fy = tgt[t * 6 + 3];
        valid = (fc < (float)Cn);
    }
    int b  = valid ? (int)fb : 0;
    int cl = valid ? (int)fc : 0;

    const float* preds[3] = {p0, p1, p2};
    const int    SS[3]    = {(int)S0, (int)S1, (int)S2};
    const float  WOs[3]   = {WO0, WO1, WO2};
    const float  WCs[3]   = {WC0, WC1, WC2};

    float corrO = 0.0f, corrC = 0.0f;

    for (int s = 0; s < 3; ++s) {
        int W = SS[s];
        unsigned myO = 0x80000000u | (unsigned)t;  // unique, matches nothing
        unsigned myC = myO;
        float vObj = 0.f, vCls = 0.f;
        if (t < NTGT && valid) {
            int gx = min((int)floorf(fx * (float)W), W - 1);
            int gy = min((int)floorf(fy * (float)W), W - 1);
            myO = ((unsigned)b << 14) | ((unsigned)gy << 7) | (unsigned)gx;
            myC = (myO << 7) | (unsigned)cl;
            // issue scattered HBM loads NOW; latency hides under dedup loop
            const float* P = preds[s];
            unsigned cell = ((unsigned)b * 3u * (unsigned)W + (unsigned)gy)
                            * (unsigned)W + (unsigned)gx;   // anchor a=0
            vObj = P[cell * CH + 4u];
            vCls = P[cell * CH + 5u + (unsigned)cl];
        }
        if (t < NTGT) { keyO[t] = myO; keyC[t] = myC; }
        __syncthreads();

        bool uo = true, uc = true;
        int lim = (t < NTGT) ? t : 0;
        #pragma unroll 4
        for (int j = 0; j < lim; ++j) {    // independent LDS b32 reads
            unsigned ko = keyO[j], kc = keyC[j];
            uo = uo && (ko != myO);
            uc = uc && (kc != myC);
        }
        if (t < NTGT && valid) {
            if (uo) corrO -= vObj * WOs[s];
            if (uc) corrC -= vCls * WCs[s];
        }
        __syncthreads();
    }

    #pragma unroll
    for (int off = 32; off > 0; off >>= 1) {
        corrO += __shfl_down(corrO, off);
        corrC += __shfl_down(corrC, off);
    }
    __shared__ float rO[4], rC[4];
    int lane = threadIdx.x & 63, wv = threadIdx.x >> 6;
    if (lane == 0) { rO[wv] = corrO; rC[wv] = corrC; }
    __syncthreads();
    if (threadIdx.x == 0)
        part[GRID] = make_float2(rO[0] + rO[1] + rO[2] + rO[3],
                                 rC[0] + rC[1] + rC[2] + rC[3]);
}

__global__ __launch_bounds__(BLOCK) void yolo_final_kernel(
    const float2* __restrict__ part, float* __restrict__ out)
{
    float o = 0.0f, c = 0.0f;
    for (unsigned i = threadIdx.x; i < GRID + 1u; i += BLOCK) {
        float2 p = part[i];
        o += p.x; c += p.y;
    }
    #pragma unroll
    for (int off = 32; off > 0; off >>= 1) {
        o += __shfl_down(o, off);
        c += __shfl_down(c, off);
    }
    __shared__ float sO[4], sC[4];
    int lane = threadIdx.x & 63, wv = threadIdx.x >> 6;
    if (lane == 0) { sO[wv] = o; sC[wv] = c; }
    __syncthreads();
    if (threadIdx.x == 0) {
        float obj = sO[0] + sO[1] + sO[2] + sO[3];
        float cls = sC[0] + sC[1] + sC[2] + sC[3];
        out[0] = obj + 0.5f * cls;   // BOX_W*0 + OBJ_W*obj + CLS_W*cls
        out[1] = 0.0f;               // total_box
        out[2] = obj;
        out[3] = cls;
    }
}

}  // namespace

extern "C" void kernel_launch(void* const* d_in, const int* in_sizes, int n_in,
                              void* d_out, int out_size, void* d_ws, size_t ws_size,
                              hipStream_t stream)
{
    const float* p0  = (const float*)d_in[0];
    const float* p1  = (const float*)d_in[1];
    const float* p2  = (const float*)d_in[2];
    const float* tgt = (const float*)d_in[3];
    float* out = (float*)d_out;
    float2* part = (float2*)d_ws;   // [0..GRID-1] sum partials, [GRID] corr

    yolo_sum_kernel  <<<GRID, BLOCK, 0, stream>>>(p0, p1, p2, part);
    yolo_corr_kernel <<<1,    BLOCK, 0, stream>>>(p0, p1, p2, tgt, part);
    yolo_final_kernel<<<1,    BLOCK, 0, stream>>>(part, out);
}